// Round 17
// baseline (105.650 us; speedup 1.0000x reference)
//
#include <hip/hip_runtime.h>
#include <hip/hip_bf16.h>

#define BB   256
#define NIN  1152
#define OO   10
#define IL   8
#define OL   16
#define ROW  (OO*OL)      // 160
#define EPSQ 1e-7f
#define NT4  8            // n per build4 block
#define BT4  32           // b per build4 block
#define NCH2 (NIN/NT4)    // 144 psum chunks

typedef unsigned short ushx8 __attribute__((ext_vector_type(8)));

__device__ __forceinline__ float bf2f(unsigned short h) {
    unsigned u = ((unsigned)h) << 16;
    return __builtin_bit_cast(float, u);
}

// K1: build u_hat (bf16) + fused psum[nc][b][160] (fp32 sum over the block's
// 8 n). Thread = (r,nl): r = hh*20+oct owns (b-half, o-octet), nl owns one n;
// each wave spans all 8 nl -> every LDS access is dense (64 distinct addrs,
// 8/bank-group = hardware minimum). w hoisted to 16 VGPR-float4s before the
// b-loop (the reuse round-16's (b,oct) mapping could not express). Per bl:
// 64 FMA + u-store + acc->red (dense) + wave-0 nl-reduce -> psum.
__global__ __launch_bounds__(320, 1) void caps_build4(
    const float* __restrict__ x, const float* __restrict__ w,
    unsigned short* __restrict__ u, float* __restrict__ psum)
{
    __shared__ float4 wl4[NT4][331];    // row-stride 331: group = 3nl+o+2k8
    __shared__ float4 redA[8][40];
    __shared__ float4 redB[8][40];
    const int t   = threadIdx.x;
    const int nl  = t & 7;
    const int r   = t >> 3;             // 0..39
    const int hh  = r / 20;             // 0..1
    const int oct = r - hh * 20;        // 0..19
    const int o   = oct >> 1;
    const int k8  = oct & 1;
    const int n0  = blockIdx.x * NT4;
    const int b0  = blockIdx.y * BT4;
    const int n   = n0 + nl;

    // stage w: 2560 float4, 8 per thread, coalesced reads, dense writes
    {
        const float4* wg = reinterpret_cast<const float4*>(w) + (size_t)n0 * 320;
        const int so = t >> 5;
        const int si = (t >> 2) & 7;
        const int sk = t & 3;
        const int sdst = so * 33 + si * 4 + sk;
        #pragma unroll
        for (int jj = 0; jj < 8; ++jj)
            wl4[jj][sdst] = wg[jj * 320 + t];
    }
    __syncthreads();

    // hoist this thread's 16 w-float4s into registers (reused for 16 b's)
    float4 wlo[IL], whi[IL];
    {
        const float4* wbase = &wl4[nl][o * 33 + k8 * 2];
        #pragma unroll
        for (int i = 0; i < IL; ++i) {
            wlo[i] = wbase[i * 4];
            whi[i] = wbase[i * 4 + 1];
        }
    }

    const float4* xg = reinterpret_cast<const float4*>(x);
    unsigned short* ub = u + ((size_t)(b0 + hh * 16) * NIN + n) * ROW
                           + o * OL + k8 * 8;
    const size_t ustride = (size_t)NIN * ROW;

    for (int bl = 0; bl < 16; ++bl) {
        const int b = b0 + hh * 16 + bl;
        const float4 x0 = xg[((size_t)b * NIN + n) * 2];
        const float4 x1 = xg[((size_t)b * NIN + n) * 2 + 1];
        const float xv[IL] = {x0.x, x0.y, x0.z, x0.w, x1.x, x1.y, x1.z, x1.w};

        float acc[8];
        #pragma unroll
        for (int j = 0; j < 8; ++j) acc[j] = 0.f;
        #pragma unroll
        for (int i = 0; i < IL; ++i) {
            acc[0] = fmaf(wlo[i].x, xv[i], acc[0]);
            acc[1] = fmaf(wlo[i].y, xv[i], acc[1]);
            acc[2] = fmaf(wlo[i].z, xv[i], acc[2]);
            acc[3] = fmaf(wlo[i].w, xv[i], acc[3]);
            acc[4] = fmaf(whi[i].x, xv[i], acc[4]);
            acc[5] = fmaf(whi[i].y, xv[i], acc[5]);
            acc[6] = fmaf(whi[i].z, xv[i], acc[6]);
            acc[7] = fmaf(whi[i].w, xv[i], acc[7]);
        }

        union { ushx8 v; __hip_bfloat162 h[4]; } pk;
        #pragma unroll
        for (int j = 0; j < 4; ++j)
            pk.h[j] = __float22bfloat162_rn(make_float2(acc[2*j], acc[2*j+1]));
        *reinterpret_cast<ushx8*>(ub + (size_t)bl * ustride) = pk.v;

        redA[nl][r] = make_float4(acc[0], acc[1], acc[2], acc[3]);
        redB[nl][r] = make_float4(acc[4], acc[5], acc[6], acc[7]);
        __syncthreads();

        if (t < 40) {
            float4 sA = redA[0][t], sB = redB[0][t];
            #pragma unroll
            for (int n2 = 1; n2 < 8; ++n2) {
                const float4 a = redA[n2][t], bv = redB[n2][t];
                sA.x += a.x;  sA.y += a.y;  sA.z += a.z;  sA.w += a.w;
                sB.x += bv.x; sB.y += bv.y; sB.z += bv.z; sB.w += bv.w;
            }
            const int hh2  = t / 20;
            const int oct2 = t - hh2 * 20;
            float* pp = psum + ((size_t)blockIdx.x * BB + b0 + hh2 * 16 + bl) * ROW
                             + oct2 * 8;
            *reinterpret_cast<float4*>(pp)     = sA;
            *reinterpret_cast<float4*>(pp + 4) = sB;
        }
        __syncthreads();
    }
}

// K2: sum psum chunks (144), *0.1 + bias, squash -> v0. 8 accumulators.
__global__ __launch_bounds__(192) void caps_squash0(
    const float* __restrict__ psum, const float* __restrict__ bias,
    float* __restrict__ v0)
{
    const int t = threadIdx.x;
    if (t >= ROW) return;
    const int b = blockIdx.x;

    float s[8];
    #pragma unroll
    for (int j = 0; j < 8; ++j) s[j] = 0.f;
    const float* pt = psum + (size_t)b * ROW + t;
    for (int ch = 0; ch < NCH2; ch += 8) {
        #pragma unroll
        for (int j = 0; j < 8; ++j)
            s[j] += pt[(size_t)(ch + j) * BB * ROW];
    }
    const float ssum = ((s[0]+s[1]) + (s[2]+s[3])) + ((s[4]+s[5]) + (s[6]+s[7]));
    const float sv = 0.1f * ssum + bias[t];

    float d = sv * sv;
    d += __shfl_xor(d, 1, 16);
    d += __shfl_xor(d, 2, 16);
    d += __shfl_xor(d, 4, 16);
    d += __shfl_xor(d, 8, 16);
    const float f = d / ((1.f + d) * sqrtf(d + EPSQ));
    v0[(size_t)b * ROW + t] = f * sv;
}

// K3: routing iterations 1,2 fused (verified round-15/16 code, untouched).
__global__ __launch_bounds__(768) void caps_route2(
    const unsigned short* __restrict__ u, const float* __restrict__ bias,
    const float* __restrict__ v0g, float* __restrict__ outv)
{
    __shared__ float lds[12][ROW];
    __shared__ float vbuf[ROW];
    const int t  = threadIdx.x;
    const int q  = t & 3;
    const int g  = t >> 2;     // 0..191
    const int wv = t >> 6;     // 0..11
    const int b  = blockIdx.x;
    const unsigned short* ub = u + (size_t)b * NIN * ROW;

    float bsv = 0.f;
    float vprev = 0.f;
    if (t < ROW) {
        bsv = bias[t];
        const float v = v0g[(size_t)b * ROW + t];
        vbuf[t] = v;
        vprev = v;
    }
    __syncthreads();

    #pragma unroll
    for (int iter = 1; iter < 3; ++iter) {
        float sp[5][8];
        #pragma unroll
        for (int j = 0; j < 5; ++j)
            #pragma unroll
            for (int e = 0; e < 8; ++e) sp[j][e] = 0.f;

        float vs[5][8];
        #pragma unroll
        for (int j = 0; j < 5; ++j) {
            #pragma unroll
            for (int e = 0; e < 8; ++e) vs[j][e] = vbuf[(q + 4 * j) * 8 + e];
        }

        for (int m = 0; m < 6; ++m) {
            const unsigned short* un = ub + (size_t)(g + m * 192) * ROW;
            float uf[5][8];
            #pragma unroll
            for (int j = 0; j < 5; ++j) {
                const ushx8 raw = *reinterpret_cast<const ushx8*>(un + (q + 4 * j) * 8);
                #pragma unroll
                for (int e = 0; e < 8; ++e) uf[j][e] = bf2f(raw[e]);
            }

            float d[5], dd[5];
            #pragma unroll
            for (int j = 0; j < 5; ++j) {
                float acc = uf[j][0] * vs[j][0];
                #pragma unroll
                for (int e = 1; e < 8; ++e) acc = fmaf(uf[j][e], vs[j][e], acc);
                acc += __shfl_xor(acc, 1, 4);
                d[j] = acc;
            }
            #pragma unroll
            for (int j = 0; j < 5; ++j) dd[j] = __shfl_xor(d[j], 2, 4);

            float mx = fmaxf(d[0], dd[0]);
            #pragma unroll
            for (int j = 1; j < 5; ++j) mx = fmaxf(mx, fmaxf(d[j], dd[j]));
            float se = 0.f, e_[5];
            #pragma unroll
            for (int j = 0; j < 5; ++j) {
                e_[j] = __expf(d[j] - mx);
                se += e_[j] + __expf(dd[j] - mx);
            }
            const float rr = 1.f / se;
            #pragma unroll
            for (int j = 0; j < 5; ++j) {
                const float c = e_[j] * rr;
                #pragma unroll
                for (int e = 0; e < 8; ++e)
                    sp[j][e] = fmaf(c, uf[j][e], sp[j][e]);
            }
        }

        #pragma unroll
        for (int j = 0; j < 5; ++j)
            #pragma unroll
            for (int e = 0; e < 8; ++e) {
                #pragma unroll
                for (int msk = 4; msk <= 32; msk <<= 1)
                    sp[j][e] += __shfl_xor(sp[j][e], msk);
            }
        if ((t & 63) < 4) {
            #pragma unroll
            for (int j = 0; j < 5; ++j)
                #pragma unroll
                for (int e = 0; e < 8; ++e)
                    lds[wv][(q + 4 * j) * 8 + e] = sp[j][e];
        }
        __syncthreads();

        if (t < ROW) {
            float ssum = 0.f;
            #pragma unroll
            for (int wvi = 0; wvi < 12; ++wvi) ssum += lds[wvi][t];
            const float sv = ssum + bsv;

            float dq = sv * sv;
            dq += __shfl_xor(dq, 1, 16);
            dq += __shfl_xor(dq, 2, 16);
            dq += __shfl_xor(dq, 4, 16);
            dq += __shfl_xor(dq, 8, 16);
            const float f = dq / ((1.f + dq) * sqrtf(dq + EPSQ));
            const float v = f * sv;

            if (iter == 1) { vbuf[t] = v + vprev; }
            else           { outv[(size_t)b * ROW + t] = v; }
        }
        __syncthreads();
    }
}

extern "C" void kernel_launch(void* const* d_in, const int* in_sizes, int n_in,
                              void* d_out, int out_size, void* d_ws, size_t ws_size,
                              hipStream_t stream) {
    const float* x    = (const float*)d_in[0]; // (B, NIN, 8, 1)
    const float* w    = (const float*)d_in[1]; // (1, NIN, O, 8, 16)
    const float* bias = (const float*)d_in[2]; // (1, 1, O, 16, 1)
    float* out = (float*)d_out;                // (B, 1, O, 16, 1)

    unsigned short* u = (unsigned short*)d_ws;                        // 94.4 MB
    float* psum = (float*)((char*)d_ws + (size_t)BB * NIN * ROW * 2); // 23.6 MB
    float* v0   = psum + (size_t)NCH2 * BB * ROW;                     // 160 KB

    caps_build4<<<dim3(NIN / NT4, BB / BT4), 320, 0, stream>>>(x, w, u, psum);
    caps_squash0<<<BB, 192, 0, stream>>>(psum, bias, v0);
    caps_route2<<<BB, 768, 0, stream>>>(u, bias, v0, out);
}

// Round 18
// 100.286 us; speedup vs baseline: 1.0535x; 1.0535x over previous
//
#include <hip/hip_runtime.h>
#include <hip/hip_bf16.h>

#define BB   256
#define NIN  1152
#define OO   10
#define IL   8
#define OL   16
#define ROW  (OO*OL)      // 160
#define EPSQ 1e-7f
#define NT   4            // n-tile per build block
#define BT   32           // b-tile per build block

typedef unsigned short ushx8 __attribute__((ext_vector_type(8)));

__device__ __forceinline__ float bf2f(unsigned short h) {
    unsigned u = ((unsigned)h) << 16;
    return __builtin_bit_cast(float, u);
}

// K1: build u_hat[b][n][o*16+k] in bf16. VERIFIED round-13/14 (~9us):
// NT=4, LDS 24.6 KB -> 6 blocks/CU. o-parity swizzle, 0 conflicts.
__global__ __launch_bounds__(160) void caps_build(
    const float* __restrict__ x, const float* __restrict__ w,
    unsigned short* __restrict__ u)
{
    __shared__ float4 wl4[NT][321];
    __shared__ float4 xl4[BT * 8];
    const int t  = threadIdx.x;
    const int n0 = blockIdx.x * NT;
    const int b0 = blockIdx.y * BT;

    const float4* wg = reinterpret_cast<const float4*>(w) + (size_t)n0 * 320;
    #pragma unroll
    for (int jj = 0; jj < 8; ++jj) {
        const int j   = t + jj * 160;
        const int row = j / 320;
        const int lin = j - row * 320;
        const int o   = lin >> 5;
        const int rem = lin & 31;
        const int i   = rem >> 2;
        const int kh  = rem & 3;
        wl4[row][(o << 5) | ((i ^ (o & 1)) << 2) | kh] = wg[j];
    }
    const float4* xg = reinterpret_cast<const float4*>(x);
    {
        int j = t;
        xl4[j] = xg[((size_t)(b0 + (j >> 3)) * NIN + n0) * 2 + (j & 7)];
        j = t + 160;
        if (j < BT * 8)
            xl4[j] = xg[((size_t)(b0 + (j >> 3)) * NIN + n0) * 2 + (j & 7)];
    }
    __syncthreads();

    const int nl = t / 40;
    const int r  = t - nl * 40;
    const int hh = r / 20;
    const int s  = r - hh * 20;
    const int o  = s >> 1;
    const int k8 = s & 1;
    const int p  = o & 1;
    const float4* wbase = &wl4[nl][(o << 5) | (k8 << 1)];
    const float4* xbase = &xl4[(hh * 16) * 8 + nl * 2];
    unsigned short* ub = u + ((size_t)(b0 + hh * 16) * NIN + n0 + nl) * ROW
                           + o * OL + k8 * 8;
    const size_t ustride = (size_t)NIN * ROW;

    for (int bl = 0; bl < 16; bl += 4) {
        float xv[4][IL];
        #pragma unroll
        for (int bb = 0; bb < 4; ++bb) {
            const float4 x0 = xbase[(bl + bb) * 8];
            const float4 x1 = xbase[(bl + bb) * 8 + 1];
            xv[bb][0] = x0.x; xv[bb][1] = x0.y; xv[bb][2] = x0.z; xv[bb][3] = x0.w;
            xv[bb][4] = x1.x; xv[bb][5] = x1.y; xv[bb][6] = x1.z; xv[bb][7] = x1.w;
        }

        float acc[4][8];
        #pragma unroll
        for (int bb = 0; bb < 4; ++bb)
            #pragma unroll
            for (int j = 0; j < 8; ++j) acc[bb][j] = 0.f;

        #pragma unroll
        for (int i = 0; i < IL; ++i) {
            const float4 wlo = wbase[(i ^ p) << 2];
            const float4 whi = wbase[((i ^ p) << 2) | 1];
            const float wv[8] = {wlo.x, wlo.y, wlo.z, wlo.w, whi.x, whi.y, whi.z, whi.w};
            #pragma unroll
            for (int bb = 0; bb < 4; ++bb)
                #pragma unroll
                for (int j = 0; j < 8; ++j)
                    acc[bb][j] = fmaf(wv[j], xv[bb][i], acc[bb][j]);
        }

        #pragma unroll
        for (int bb = 0; bb < 4; ++bb) {
            union { ushx8 v; __hip_bfloat162 h[4]; } pk;
            #pragma unroll
            for (int j = 0; j < 4; ++j)
                pk.h[j] = __float22bfloat162_rn(make_float2(acc[bb][2*j], acc[bb][2*j+1]));
            *reinterpret_cast<ushx8*>(ub + (size_t)(bl + bb) * ustride) = pk.v;
        }
    }
}

// K2: one routing sweep, SPLIT over 2 blocks per b (grid (BB,2) = 2 blocks/CU
// = 24 waves/CU; the single-block route3 was latency-bound at 12 waves/CU).
// Each block: 768 thr = 192 4-lane groups x 3 m-steps = 576 n. Inner math is
// the verified route2/route3 body; vs read from global vin. Writes fp32
// partial[split][b][160]; caps_finish combines.
template<int ITER>
__global__ __launch_bounds__(768) void caps_pass(
    const unsigned short* __restrict__ u, const float* __restrict__ vin,
    float* __restrict__ partial)
{
    __shared__ float lds[12][ROW];
    const int t  = threadIdx.x;
    const int q  = t & 3;
    const int g  = t >> 2;     // 0..191
    const int wv = t >> 6;     // 0..11
    const int b  = blockIdx.x;
    const int sp0 = blockIdx.y;            // split 0/1
    const unsigned short* ub = u + ((size_t)b * NIN + (size_t)sp0 * 576) * ROW;

    float sp[5][8];
    #pragma unroll
    for (int j = 0; j < 5; ++j)
        #pragma unroll
        for (int e = 0; e < 8; ++e) sp[j][e] = 0.f;

    if (ITER == 0) {
        for (int m = 0; m < 3; ++m) {
            const unsigned short* un = ub + (size_t)(g + m * 192) * ROW;
            #pragma unroll
            for (int j = 0; j < 5; ++j) {
                const ushx8 raw = *reinterpret_cast<const ushx8*>(un + (q + 4 * j) * 8);
                #pragma unroll
                for (int e = 0; e < 8; ++e) sp[j][e] += bf2f(raw[e]);
            }
        }
    } else {
        float vs[5][8];
        #pragma unroll
        for (int j = 0; j < 5; ++j) {
            const float* vp = vin + (size_t)b * ROW + (q + 4 * j) * 8;
            const float4 a  = *reinterpret_cast<const float4*>(vp);
            const float4 c4 = *reinterpret_cast<const float4*>(vp + 4);
            vs[j][0] = a.x;  vs[j][1] = a.y;  vs[j][2] = a.z;  vs[j][3] = a.w;
            vs[j][4] = c4.x; vs[j][5] = c4.y; vs[j][6] = c4.z; vs[j][7] = c4.w;
        }

        for (int m = 0; m < 3; ++m) {
            const unsigned short* un = ub + (size_t)(g + m * 192) * ROW;
            float uf[5][8];
            #pragma unroll
            for (int j = 0; j < 5; ++j) {
                const ushx8 raw = *reinterpret_cast<const ushx8*>(un + (q + 4 * j) * 8);
                #pragma unroll
                for (int e = 0; e < 8; ++e) uf[j][e] = bf2f(raw[e]);
            }

            // own-parity dots (half-k), combine halves, then swap parity
            float d[5], dd[5];
            #pragma unroll
            for (int j = 0; j < 5; ++j) {
                float acc = uf[j][0] * vs[j][0];
                #pragma unroll
                for (int e = 1; e < 8; ++e) acc = fmaf(uf[j][e], vs[j][e], acc);
                acc += __shfl_xor(acc, 1, 4);
                d[j] = acc;
            }
            #pragma unroll
            for (int j = 0; j < 5; ++j) dd[j] = __shfl_xor(d[j], 2, 4);

            float mx = fmaxf(d[0], dd[0]);
            #pragma unroll
            for (int j = 1; j < 5; ++j) mx = fmaxf(mx, fmaxf(d[j], dd[j]));
            float se = 0.f, e_[5];
            #pragma unroll
            for (int j = 0; j < 5; ++j) {
                e_[j] = __expf(d[j] - mx);
                se += e_[j] + __expf(dd[j] - mx);
            }
            const float rr = 1.f / se;
            #pragma unroll
            for (int j = 0; j < 5; ++j) {
                const float c = e_[j] * rr;
                #pragma unroll
                for (int e = 0; e < 8; ++e)
                    sp[j][e] = fmaf(c, uf[j][e], sp[j][e]);
            }
        }
    }

    // butterfly over the 16 groups of each wave (masks preserve q)
    #pragma unroll
    for (int j = 0; j < 5; ++j)
        #pragma unroll
        for (int e = 0; e < 8; ++e) {
            #pragma unroll
            for (int msk = 4; msk <= 32; msk <<= 1)
                sp[j][e] += __shfl_xor(sp[j][e], msk);
        }
    if ((t & 63) < 4) {
        #pragma unroll
        for (int j = 0; j < 5; ++j)
            #pragma unroll
            for (int e = 0; e < 8; ++e)
                lds[wv][(q + 4 * j) * 8 + e] = sp[j][e];
    }
    __syncthreads();

    if (t < ROW) {
        float ssum = 0.f;
        #pragma unroll
        for (int wvi = 0; wvi < 12; ++wvi) ssum += lds[wvi][t];
        partial[((size_t)sp0 * BB + b) * ROW + t] = ssum;
    }
}

// K3: combine the 2 split-partials + bias, squash; optional prevAdd.
__global__ __launch_bounds__(192) void caps_finish(
    const float* __restrict__ partial, const float* __restrict__ bias,
    const float* __restrict__ prevAdd, float* __restrict__ outv, float scale)
{
    const int t = threadIdx.x;
    if (t >= ROW) return;
    const int b = blockIdx.x;

    const float s = scale * (partial[(size_t)b * ROW + t]
                           + partial[((size_t)BB + b) * ROW + t]) + bias[t];

    float d = s * s;
    d += __shfl_xor(d, 1, 16);
    d += __shfl_xor(d, 2, 16);
    d += __shfl_xor(d, 4, 16);
    d += __shfl_xor(d, 8, 16);
    const float f = d / ((1.f + d) * sqrtf(d + EPSQ));
    float v = f * s;
    if (prevAdd) v += prevAdd[(size_t)b * ROW + t];
    outv[(size_t)b * ROW + t] = v;
}

extern "C" void kernel_launch(void* const* d_in, const int* in_sizes, int n_in,
                              void* d_out, int out_size, void* d_ws, size_t ws_size,
                              hipStream_t stream) {
    const float* x    = (const float*)d_in[0]; // (B, NIN, 8, 1)
    const float* w    = (const float*)d_in[1]; // (1, NIN, O, 8, 16)
    const float* bias = (const float*)d_in[2]; // (1, 1, O, 16, 1)
    float* out = (float*)d_out;                // (B, 1, O, 16, 1)

    unsigned short* u = (unsigned short*)d_ws;                        // 94.4 MB
    float* partial = (float*)((char*)d_ws + (size_t)BB * NIN * ROW * 2); // 327 KB
    float* v0  = partial + (size_t)2 * BB * ROW;
    float* vsb = v0 + (size_t)BB * ROW;

    const dim3 pg(BB, 2);

    caps_build<<<dim3(NIN / NT, BB / BT), 160, 0, stream>>>(x, w, u);
    // iter0: uniform c -> v0
    caps_pass<0><<<pg, 768, 0, stream>>>(u, nullptr, partial);
    caps_finish<<<BB, 192, 0, stream>>>(partial, bias, nullptr, v0, 0.1f);
    // iter1: c = softmax(u.v0) -> vsb = v0 + v1
    caps_pass<1><<<pg, 768, 0, stream>>>(u, v0, partial);
    caps_finish<<<BB, 192, 0, stream>>>(partial, bias, v0, vsb, 1.0f);
    // iter2: c = softmax(u.(v0+v1)) -> out
    caps_pass<2><<<pg, 768, 0, stream>>>(u, vsb, partial);
    caps_finish<<<BB, 192, 0, stream>>>(partial, bias, nullptr, out, 1.0f);
}